// Round 7
// baseline (130.052 us; speedup 1.0000x reference)
//
#include <hip/hip_runtime.h>
#include <math.h>

constexpr int B = 16, F = 64, E = 16, H = 64, W = 64;
constexpr int XP = 66;          // padded x dim (1 zero col each side)
constexpr int CP = 72;          // LDS o-dim pad (16B-aligned bf16x8 rows)
constexpr int YSTRIDE = XP * F; // 4224 elems per (b,y) row in xTs

typedef __bf16 bf16x8 __attribute__((ext_vector_type(8)));
typedef __bf16 bf16x4 __attribute__((ext_vector_type(4)));
typedef float f32x16 __attribute__((ext_vector_type(16)));
typedef float f32x4 __attribute__((ext_vector_type(4)));

// ---------------------------------------------------------------------------
// prep: blk<1024: transpose state -> xTs[b][y][x+1][c] bf16 (borders zeroed)
//       blk<1168: repack weights (wA1[o][t*64+c], wA2[e][t*64+c], wT3b=bf16(c3_w))
//       else    : zero d_out[0..16383] (the (B,E,F) accumulator region)
// ---------------------------------------------------------------------------
__global__ __launch_bounds__(256) void prep_kernel(
    const float* __restrict__ state, const float* __restrict__ pre_w,
    const float* __restrict__ attn_w, const float* __restrict__ c3_w,
    __bf16* __restrict__ xTs, __bf16* __restrict__ wA1,
    __bf16* __restrict__ wA2, __bf16* __restrict__ wT3b,
    float* __restrict__ out0)
{
    __shared__ float s_t[64][68];
    const int blk = blockIdx.x;
    const int tid = threadIdx.x;

    if (blk < 1024) {
        const int b = blk >> 6, y = blk & 63;
        {
            int c = tid >> 2, x0 = (tid & 3) * 16;
            const float* src = state + ((size_t)(b * F + c) * H + y) * W + x0;
            #pragma unroll
            for (int q = 0; q < 4; ++q)
                *(float4*)&s_t[c][x0 + 4 * q] = *(const float4*)(src + 4 * q);
        }
        __syncthreads();
        __bf16* dst = xTs + (size_t)(b * H + y) * YSTRIDE;
        #pragma unroll
        for (int i = 0; i < 2; ++i) {
            int t = tid + i * 256;
            int x = t >> 3, cg = t & 7;
            bf16x8 v;
            #pragma unroll
            for (int j = 0; j < 8; ++j) v[j] = (__bf16)s_t[cg * 8 + j][x];
            *(bf16x8*)(dst + (x + 1) * F + cg * 8) = v;
        }
        if (tid < 16) {
            int bd = tid >> 3, cg = tid & 7;
            bf16x8 z = {};
            *(bf16x8*)(dst + (bd ? 65 : 0) * F + cg * 8) = z;
        }
    } else if (blk < 1168) {
        int idx = (blk - 1024) * 256 + tid;
        if (idx < 64 * 576) {
            int o = idx / 576, rem = idx - o * 576, t = rem >> 6, c = rem & 63;
            wA1[idx] = (__bf16)pre_w[(o * 64 + c) * 9 + t];
        }
        if (idx < 16 * 576) {
            int e = idx / 576, rem = idx - e * 576, t = rem >> 6, c = rem & 63;
            wA2[idx] = (__bf16)attn_w[(e * 64 + c) * 9 + t];
        }
        if (idx < 64 * 64) {
            wT3b[idx] = (__bf16)c3_w[idx];   // already [o][f] row-major
        }
    } else {
        int idx = (blk - 1168) * 256 + tid;  // 16 blocks cover 16384 floats
        float4 z = {0.f, 0.f, 0.f, 0.f};
        *(float4*)(out0 + idx * 4) = z;
    }
}

// ---------------------------------------------------------------------------
// mega: conv1 (redundant, 4 rows/block, B-frags direct from global xTs)
//       -> LDS sxo[4][XP][CP] bf16 -> conv2 (MFMA) -> sigmoid -> attn_out+LDS
//       -> sproj (MFMA from global xTs) -> relu-reduce -> atomicAdd out.
// block = (b, row-pair yp); 512 blocks; LDS 38 KB -> 2 blocks/CU.
// ---------------------------------------------------------------------------
__global__ __launch_bounds__(256) void mega_kernel(
    const __bf16* __restrict__ xTs, const __bf16* __restrict__ wA1,
    const __bf16* __restrict__ wA2, const __bf16* __restrict__ wT3b,
    const float* __restrict__ pre_b, const float* __restrict__ attn_b,
    const float* __restrict__ c3_b,
    float* __restrict__ attn_out, float* __restrict__ out)
{
    __shared__ __align__(16) char smem[4 * XP * CP * 2];     // 38016 B
    const int b = blockIdx.y, yp = blockIdx.x;
    const int tid = threadIdx.x;
    const int wave = tid >> 6, lane = tid & 63;
    const int y0 = yp * 2;

    __bf16* sxo = (__bf16*)smem;                             // [4][XP][CP]
    float (*s_attn)[64][16] = (float(*)[64][16])smem;        // [2][64][16] (overlay)
    float (*s_sp)[68] = (float(*)[68])(smem + 8192);         // [64][68]    (overlay)

    // ---------- conv1: wave np = one output row yr = y0-1+np ----------
    {
        const int n = lane & 31, kh = lane >> 5;
        const int yr = y0 - 1 + wave;
        f32x16 acc[4] = {};   // [mt*2+nt]
        if (yr >= 0 && yr < H) {
            #pragma unroll
            for (int dy = 0; dy < 3; ++dy) {
                const int row = yr - 1 + dy;
                if (row >= 0 && row < H) {
                    const __bf16* rbase = xTs + (size_t)(b * H + row) * YSTRIDE;
                    #pragma unroll
                    for (int dx = 0; dx < 3; ++dx) {
                        const int t9 = dy * 3 + dx;
                        #pragma unroll
                        for (int cq = 0; cq < 4; ++cq) {
                            const int ko = cq * 16 + kh * 8;
                            bf16x8 a0 = *(const bf16x8*)(wA1 + n * 576 + t9 * 64 + ko);
                            bf16x8 a1 = *(const bf16x8*)(wA1 + (32 + n) * 576 + t9 * 64 + ko);
                            bf16x8 b0 = *(const bf16x8*)(rbase + (n + dx) * F + ko);
                            bf16x8 b1 = *(const bf16x8*)(rbase + (n + dx + 32) * F + ko);
                            acc[0] = __builtin_amdgcn_mfma_f32_32x32x16_bf16(a0, b0, acc[0], 0, 0, 0);
                            acc[1] = __builtin_amdgcn_mfma_f32_32x32x16_bf16(a0, b1, acc[1], 0, 0, 0);
                            acc[2] = __builtin_amdgcn_mfma_f32_32x32x16_bf16(a1, b0, acc[2], 0, 0, 0);
                            acc[3] = __builtin_amdgcn_mfma_f32_32x32x16_bf16(a1, b1, acc[3], 0, 0, 0);
                        }
                    }
                }
            }
            // epilogue: D row o = mt*32 + kh*4 + g*8 + r, col x = nt*32 + n
            __bf16* orow = sxo + wave * XP * CP;
            #pragma unroll
            for (int mt = 0; mt < 2; ++mt)
                #pragma unroll
                for (int g = 0; g < 4; ++g) {
                    int o0 = mt * 32 + kh * 4 + g * 8;
                    f32x4 b4 = *(const f32x4*)(pre_b + o0);
                    bf16x4 v0, v1;
                    #pragma unroll
                    for (int r = 0; r < 4; ++r) {
                        v0[r] = (__bf16)fmaxf(acc[mt * 2 + 0][g * 4 + r] + b4[r], 0.f);
                        v1[r] = (__bf16)fmaxf(acc[mt * 2 + 1][g * 4 + r] + b4[r], 0.f);
                    }
                    *(bf16x4*)(orow + (n + 1) * CP + o0) = v0;
                    *(bf16x4*)(orow + (n + 33) * CP + o0) = v1;
                }
        } else {
            // y-halo row: genuine zero padding for conv2
            __bf16* orow = sxo + wave * XP * CP;
            bf16x4 z = {};
            #pragma unroll
            for (int mt = 0; mt < 2; ++mt)
                #pragma unroll
                for (int g = 0; g < 4; ++g) {
                    int o0 = mt * 32 + kh * 4 + g * 8;
                    *(bf16x4*)(orow + (n + 1) * CP + o0) = z;
                    *(bf16x4*)(orow + (n + 33) * CP + o0) = z;
                }
        }
        if (tid < 64) {   // zero x-borders (cols 0 and 65) of all 4 rows
            int r = tid >> 4, bd = (tid >> 3) & 1, cg = tid & 7;
            bf16x8 z = {};
            *(bf16x8*)(sxo + (r * XP + (bd ? 65 : 0)) * CP + cg * 8) = z;
        }
    }
    __syncthreads();

    // ---------- conv2: wave = (row rw, x-half nt2) ----------
    const int rw = wave >> 1, nt2 = wave & 1;
    const int n16 = lane & 15, quad = lane >> 4;
    f32x4 acc2[2] = {};
    {
        const __bf16* aB = wA2 + n16 * 576 + quad * 8;
        #pragma unroll
        for (int dy = 0; dy < 3; ++dy)
            #pragma unroll
            for (int dx = 0; dx < 3; ++dx) {
                const int t9 = dy * 3 + dx;
                #pragma unroll
                for (int cq = 0; cq < 2; ++cq) {
                    bf16x8 a = *(const bf16x8*)(aB + t9 * 64 + cq * 32);
                    #pragma unroll
                    for (int i = 0; i < 2; ++i) {
                        const __bf16* bp = sxo +
                            ((rw + dy) * XP + (nt2 * 32 + i * 16 + n16 + dx)) * CP
                            + quad * 8 + cq * 32;
                        acc2[i] = __builtin_amdgcn_mfma_f32_16x16x32_bf16(
                            a, *(const bf16x8*)bp, acc2[i], 0, 0, 0);
                    }
                }
            }
    }
    __syncthreads();   // all waves done reading sxo; s_attn/s_sp overlay it

    #pragma unroll
    for (int i = 0; i < 2; ++i) {
        int x = nt2 * 32 + i * 16 + n16;
        #pragma unroll
        for (int r = 0; r < 4; ++r) {
            int e = quad * 4 + r;
            float val = acc2[i][r] + attn_b[e];
            float sg = 1.f / (1.f + __expf(-val));
            attn_out[((size_t)(b * E + e) * H + (y0 + rw)) * W + x] = sg;
            s_attn[rw][x][e] = sg;
        }
    }
    __syncthreads();

    // ---------- sproj + reduce ----------
    const int combo = tid & 63;
    const int eg = combo >> 4, og = combo & 15, psub = tid >> 6;
    f32x4 cb4 = ((const f32x4*)c3_b)[og];
    float vsum[4] = {0.f, 0.f, 0.f, 0.f};

    for (int rr = 0; rr < 2; ++rr) {
        {   // sproj via MFMA from global xTs row y0+rr
            const int mt = wave & 1, nt = wave >> 1;
            const int n = lane & 31, kh = lane >> 5;
            const __bf16* bBase = xTs + (size_t)(b * H + y0 + rr) * YSTRIDE
                                  + (nt * 32 + n + 1) * F + kh * 8;
            const __bf16* aBase = wT3b + (mt * 32 + n) * 64 + kh * 8;
            f32x16 acc = {};
            #pragma unroll
            for (int cq = 0; cq < 4; ++cq) {
                bf16x8 a  = *(const bf16x8*)(aBase + cq * 16);
                bf16x8 bb = *(const bf16x8*)(bBase + cq * 16);
                acc = __builtin_amdgcn_mfma_f32_32x32x16_bf16(a, bb, acc, 0, 0, 0);
            }
            #pragma unroll
            for (int g = 0; g < 4; ++g)
                #pragma unroll
                for (int r = 0; r < 4; ++r)
                    s_sp[nt * 32 + n][mt * 32 + kh * 4 + g * 8 + r] = acc[g * 4 + r];
        }
        __syncthreads();

        float accl[4][4] = {};
        #pragma unroll 2
        for (int pp = 0; pp < 16; ++pp) {
            int p = psub * 16 + pp;
            f32x4 a4 = *(const f32x4*)&s_attn[rr][p][eg * 4];
            f32x4 s4 = *(const f32x4*)&s_sp[p][og * 4];
            #pragma unroll
            for (int i = 0; i < 4; ++i)
                #pragma unroll
                for (int j = 0; j < 4; ++j)
                    accl[i][j] += fmaxf(fmaf(a4[i], s4[j], cb4[j]), 0.f);
        }
        __syncthreads();
        float* s_part = &s_sp[0][0];           // 4096 floats, overlays s_sp
        #pragma unroll
        for (int i = 0; i < 4; ++i)
            #pragma unroll
            for (int j = 0; j < 4; ++j)
                s_part[(psub * 64 + combo) * 16 + i * 4 + j] = accl[i][j];
        __syncthreads();
        {
            int cmb = tid >> 2, ii = tid & 3;
            #pragma unroll
            for (int j = 0; j < 4; ++j) {
                float v = 0.f;
                #pragma unroll
                for (int ps = 0; ps < 4; ++ps)
                    v += s_part[(ps * 64 + cmb) * 16 + ii * 4 + j];
                vsum[j] += v;
            }
        }
        __syncthreads();   // s_part reads done before next rr overwrites s_sp
    }
    {
        int cmb = tid >> 2, ii = tid & 3;
        int e = (cmb >> 4) * 4 + ii;
        #pragma unroll
        for (int j = 0; j < 4; ++j) {
            int o = (cmb & 15) * 4 + j;
            float add = vsum[j] * (1.f / 4356.f);
            if (yp == 0) add += 260.f * fmaxf(c3_b[o], 0.f) * (1.f / 4356.f);
            atomicAdd(&out[(b * E + e) * F + o], add);
        }
    }
}

// ---------------------------------------------------------------------------
extern "C" void kernel_launch(void* const* d_in, const int* in_sizes, int n_in,
                              void* d_out, int out_size, void* d_ws, size_t ws_size,
                              hipStream_t stream) {
    (void)in_sizes; (void)n_in; (void)out_size; (void)ws_size;
    const float* state  = (const float*)d_in[0];
    const float* pre_w  = (const float*)d_in[1];
    const float* pre_b  = (const float*)d_in[2];
    const float* attn_w = (const float*)d_in[3];
    const float* attn_b = (const float*)d_in[4];
    const float* c3_w   = (const float*)d_in[5];
    const float* c3_b   = (const float*)d_in[6];

    float* out      = (float*)d_out;
    float* attn_out = out + B * E * F;

    char* ws = (char*)d_ws;
    constexpr size_t XT_BYTES = (size_t)B * H * YSTRIDE * 2;   // 8,650,752
    __bf16* xTs  = (__bf16*)ws;
    __bf16* wA1  = (__bf16*)(ws + XT_BYTES);
    __bf16* wA2  = (__bf16*)(ws + XT_BYTES + 73728);
    __bf16* wT3b = (__bf16*)(ws + XT_BYTES + 73728 + 18432);

    prep_kernel<<<1184, 256, 0, stream>>>(state, pre_w, attn_w, c3_w,
                                          xTs, wA1, wA2, wT3b, out);
    mega_kernel<<<dim3(H / 2, B), 256, 0, stream>>>(xTs, wA1, wA2, wT3b,
                                                    pre_b, attn_b, c3_b,
                                                    attn_out, out);
}

// Round 8
// 116.138 us; speedup vs baseline: 1.1198x; 1.1198x over previous
//
#include <hip/hip_runtime.h>
#include <math.h>

constexpr int B = 16, F = 64, E = 16, H = 64, W = 64;
constexpr int XP = 66;          // padded x dim (1 zero col each side)
constexpr int CP = 72;          // LDS inner pad (16B-aligned bf16x8 rows)
constexpr int YSTRIDE = XP * F; // 4224 elems per (b,y) row in xTs

typedef __bf16 bf16x8 __attribute__((ext_vector_type(8)));
typedef __bf16 bf16x4 __attribute__((ext_vector_type(4)));
typedef float f32x16 __attribute__((ext_vector_type(16)));
typedef float f32x4 __attribute__((ext_vector_type(4)));

// ---------------------------------------------------------------------------
// prep: blk<1024: transpose state -> xTs[b][y][x+1][c] bf16 (borders zeroed)
//       blk<1168: repack weights (wA1[o][t*64+c], wA2[e][t*64+c], wT3b=bf16(c3_w))
//       else    : zero d_out[0..16383] (the (B,E,F) accumulator region)
// ---------------------------------------------------------------------------
__global__ __launch_bounds__(256) void prep_kernel(
    const float* __restrict__ state, const float* __restrict__ pre_w,
    const float* __restrict__ attn_w, const float* __restrict__ c3_w,
    __bf16* __restrict__ xTs, __bf16* __restrict__ wA1,
    __bf16* __restrict__ wA2, __bf16* __restrict__ wT3b,
    float* __restrict__ out0)
{
    __shared__ float s_t[64][68];
    const int blk = blockIdx.x;
    const int tid = threadIdx.x;

    if (blk < 1024) {
        const int b = blk >> 6, y = blk & 63;
        {
            int c = tid >> 2, x0 = (tid & 3) * 16;
            const float* src = state + ((size_t)(b * F + c) * H + y) * W + x0;
            #pragma unroll
            for (int q = 0; q < 4; ++q)
                *(float4*)&s_t[c][x0 + 4 * q] = *(const float4*)(src + 4 * q);
        }
        __syncthreads();
        __bf16* dst = xTs + (size_t)(b * H + y) * YSTRIDE;
        #pragma unroll
        for (int i = 0; i < 2; ++i) {
            int t = tid + i * 256;
            int x = t >> 3, cg = t & 7;
            bf16x8 v;
            #pragma unroll
            for (int j = 0; j < 8; ++j) v[j] = (__bf16)s_t[cg * 8 + j][x];
            *(bf16x8*)(dst + (x + 1) * F + cg * 8) = v;
        }
        if (tid < 16) {
            int bd = tid >> 3, cg = tid & 7;
            bf16x8 z = {};
            *(bf16x8*)(dst + (bd ? 65 : 0) * F + cg * 8) = z;
        }
    } else if (blk < 1168) {
        int idx = (blk - 1024) * 256 + tid;
        if (idx < 64 * 576) {
            int o = idx / 576, rem = idx - o * 576, t = rem >> 6, c = rem & 63;
            wA1[idx] = (__bf16)pre_w[(o * 64 + c) * 9 + t];
        }
        if (idx < 16 * 576) {
            int e = idx / 576, rem = idx - e * 576, t = rem >> 6, c = rem & 63;
            wA2[idx] = (__bf16)attn_w[(e * 64 + c) * 9 + t];
        }
        if (idx < 64 * 64) {
            wT3b[idx] = (__bf16)c3_w[idx];   // already [o][f] row-major
        }
    } else {
        int idx = (blk - 1168) * 256 + tid;  // 16 blocks cover 16384 floats
        float4 z = {0.f, 0.f, 0.f, 0.f};
        *(float4*)(out0 + idx * 4) = z;
    }
}

// ---------------------------------------------------------------------------
// mega v2: stage xTs rows y0-2..y0+3 -> LDS (coalesced) -> conv1 from LDS
//   (4 rows incl. y-halo, B-frags via ds_read_b128) -> overlay conv1 out in
//   LDS -> conv2 (MFMA) -> sigmoid -> attn_out + s_attn -> sproj (MFMA,
//   global xTs) -> relu-reduce -> atomicAdd out.
// block = (b, row-pair yp); 512 blocks; LDS 63.6 KB static -> 2 blocks/CU.
// ---------------------------------------------------------------------------
__global__ __launch_bounds__(256) void mega_kernel(
    const __bf16* __restrict__ xTs, const __bf16* __restrict__ wA1,
    const __bf16* __restrict__ wA2, const __bf16* __restrict__ wT3b,
    const float* __restrict__ pre_b, const float* __restrict__ attn_b,
    const float* __restrict__ c3_b,
    float* __restrict__ attn_out, float* __restrict__ out)
{
    __shared__ __align__(16) char smem[63616];
    const int b = blockIdx.y, yp = blockIdx.x;
    const int tid = threadIdx.x;
    const int wave = tid >> 6, lane = tid & 63;
    const int y0 = yp * 2;

    __bf16* s_in = (__bf16*)smem;                            // [6][XP][CP] (dead after conv1)
    __bf16* sxo  = (__bf16*)smem;                            // [4][XP][CP] (overlay)
    float (*s_attn)[64][16] = (float(*)[64][16])(smem + 38016);  // [2][64][16]
    float (*s_sp)[68] = (float(*)[68])(smem + 46208);            // [64][68]

    // ---------- stage 6 input rows (coalesced; OOB rows zero) ----------
    for (int t = tid; t < 6 * XP * 8; t += 256) {
        int r = t / (XP * 8), rem = t - r * (XP * 8);
        int x = rem >> 3, cg = rem & 7;
        int yy = y0 - 2 + r;
        bf16x8 v = {};
        if (yy >= 0 && yy < H)
            v = *(const bf16x8*)(xTs + (size_t)(b * H + yy) * YSTRIDE + x * F + cg * 8);
        *(bf16x8*)(s_in + (r * XP + x) * CP + cg * 8) = v;
    }
    __syncthreads();

    // ---------- conv1: wave -> output row yr = y0-1+wave, full 64 o x 64 x ----
    {
        const int n = lane & 31, kh = lane >> 5;
        const int yr = y0 - 1 + wave;
        f32x16 acc[4] = {};   // [mt*2+nt]
        const bool valid = (yr >= 0 && yr < H);
        if (valid) {
            #pragma unroll
            for (int dy = 0; dy < 3; ++dy) {
                // input row index in s_in: (yr-1+dy) - (y0-2) = wave + dy
                #pragma unroll
                for (int dx = 0; dx < 3; ++dx) {
                    const int t9 = dy * 3 + dx;
                    const __bf16* bB = s_in + ((wave + dy) * XP + (n + dx)) * CP + kh * 8;
                    #pragma unroll
                    for (int cq = 0; cq < 4; ++cq) {
                        const int ko = cq * 16 + kh * 8;
                        bf16x8 a0 = *(const bf16x8*)(wA1 + n * 576 + t9 * 64 + ko);
                        bf16x8 a1 = *(const bf16x8*)(wA1 + (32 + n) * 576 + t9 * 64 + ko);
                        bf16x8 b0 = *(const bf16x8*)(bB + cq * 16);
                        bf16x8 b1 = *(const bf16x8*)(bB + 32 * CP + cq * 16);
                        acc[0] = __builtin_amdgcn_mfma_f32_32x32x16_bf16(a0, b0, acc[0], 0, 0, 0);
                        acc[1] = __builtin_amdgcn_mfma_f32_32x32x16_bf16(a0, b1, acc[1], 0, 0, 0);
                        acc[2] = __builtin_amdgcn_mfma_f32_32x32x16_bf16(a1, b0, acc[2], 0, 0, 0);
                        acc[3] = __builtin_amdgcn_mfma_f32_32x32x16_bf16(a1, b1, acc[3], 0, 0, 0);
                    }
                }
            }
        }
        __syncthreads();   // s_in reads complete; sxo overlay may be written

        // epilogue: D row o = mt*32 + kh*4 + g*8 + r, col x = nt*32 + n
        __bf16* orow = sxo + wave * XP * CP;
        #pragma unroll
        for (int mt = 0; mt < 2; ++mt)
            #pragma unroll
            for (int g = 0; g < 4; ++g) {
                int o0 = mt * 32 + kh * 4 + g * 8;
                f32x4 b4 = *(const f32x4*)(pre_b + o0);
                bf16x4 v0 = {}, v1 = {};
                if (valid) {
                    #pragma unroll
                    for (int r = 0; r < 4; ++r) {
                        v0[r] = (__bf16)fmaxf(acc[mt * 2 + 0][g * 4 + r] + b4[r], 0.f);
                        v1[r] = (__bf16)fmaxf(acc[mt * 2 + 1][g * 4 + r] + b4[r], 0.f);
                    }
                }
                *(bf16x4*)(orow + (n + 1) * CP + o0) = v0;
                *(bf16x4*)(orow + (n + 33) * CP + o0) = v1;
            }
        if (tid < 64) {   // zero x-borders (cols 0 and 65) of all 4 rows
            int r = tid >> 4, bd = (tid >> 3) & 1, cg = tid & 7;
            bf16x8 z = {};
            *(bf16x8*)(sxo + (r * XP + (bd ? 65 : 0)) * CP + cg * 8) = z;
        }
    }
    __syncthreads();

    // ---------- conv2: wave = (row rw, x-half nt2) ----------
    const int rw = wave >> 1, nt2 = wave & 1;
    const int n16 = lane & 15, quad = lane >> 4;
    f32x4 acc2[2] = {};
    {
        const __bf16* aB = wA2 + n16 * 576 + quad * 8;
        #pragma unroll
        for (int dy = 0; dy < 3; ++dy)
            #pragma unroll
            for (int dx = 0; dx < 3; ++dx) {
                const int t9 = dy * 3 + dx;
                #pragma unroll
                for (int cq = 0; cq < 2; ++cq) {
                    bf16x8 a = *(const bf16x8*)(aB + t9 * 64 + cq * 32);
                    #pragma unroll
                    for (int i = 0; i < 2; ++i) {
                        const __bf16* bp = sxo +
                            ((rw + dy) * XP + (nt2 * 32 + i * 16 + n16 + dx)) * CP
                            + quad * 8 + cq * 32;
                        acc2[i] = __builtin_amdgcn_mfma_f32_16x16x32_bf16(
                            a, *(const bf16x8*)bp, acc2[i], 0, 0, 0);
                    }
                }
            }
    }

    #pragma unroll
    for (int i = 0; i < 2; ++i) {
        int x = nt2 * 32 + i * 16 + n16;
        #pragma unroll
        for (int r = 0; r < 4; ++r) {
            int e = quad * 4 + r;
            float val = acc2[i][r] + attn_b[e];
            float sg = 1.f / (1.f + __expf(-val));
            attn_out[((size_t)(b * E + e) * H + (y0 + rw)) * W + x] = sg;
            s_attn[rw][x][e] = sg;   // non-overlapping region; no sync needed
        }
    }
    __syncthreads();

    // ---------- sproj + reduce ----------
    const int combo = tid & 63;
    const int eg = combo >> 4, og = combo & 15, psub = tid >> 6;
    f32x4 cb4 = ((const f32x4*)c3_b)[og];
    float vsum[4] = {0.f, 0.f, 0.f, 0.f};

    for (int rr = 0; rr < 2; ++rr) {
        {   // sproj via MFMA from global xTs row y0+rr
            const int mt = wave & 1, nt = wave >> 1;
            const int n = lane & 31, kh = lane >> 5;
            const __bf16* bBase = xTs + (size_t)(b * H + y0 + rr) * YSTRIDE
                                  + (nt * 32 + n + 1) * F + kh * 8;
            const __bf16* aBase = wT3b + (mt * 32 + n) * 64 + kh * 8;
            f32x16 acc = {};
            #pragma unroll
            for (int cq = 0; cq < 4; ++cq) {
                bf16x8 a  = *(const bf16x8*)(aBase + cq * 16);
                bf16x8 bb = *(const bf16x8*)(bBase + cq * 16);
                acc = __builtin_amdgcn_mfma_f32_32x32x16_bf16(a, bb, acc, 0, 0, 0);
            }
            #pragma unroll
            for (int g = 0; g < 4; ++g)
                #pragma unroll
                for (int r = 0; r < 4; ++r)
                    s_sp[nt * 32 + n][mt * 32 + kh * 4 + g * 8 + r] = acc[g * 4 + r];
        }
        __syncthreads();

        float accl[4][4] = {};
        #pragma unroll 2
        for (int pp = 0; pp < 16; ++pp) {
            int p = psub * 16 + pp;
            f32x4 a4 = *(const f32x4*)&s_attn[rr][p][eg * 4];
            f32x4 s4 = *(const f32x4*)&s_sp[p][og * 4];
            #pragma unroll
            for (int i = 0; i < 4; ++i)
                #pragma unroll
                for (int j = 0; j < 4; ++j)
                    accl[i][j] += fmaxf(fmaf(a4[i], s4[j], cb4[j]), 0.f);
        }
        __syncthreads();
        float* s_part = &s_sp[0][0];           // 4096 floats, overlays s_sp
        #pragma unroll
        for (int i = 0; i < 4; ++i)
            #pragma unroll
            for (int j = 0; j < 4; ++j)
                s_part[(psub * 64 + combo) * 16 + i * 4 + j] = accl[i][j];
        __syncthreads();
        {
            int cmb = tid >> 2, ii = tid & 3;
            #pragma unroll
            for (int j = 0; j < 4; ++j) {
                float v = 0.f;
                #pragma unroll
                for (int ps = 0; ps < 4; ++ps)
                    v += s_part[(ps * 64 + cmb) * 16 + ii * 4 + j];
                vsum[j] += v;
            }
        }
        __syncthreads();   // s_part reads done before next rr overwrites s_sp
    }
    {
        int cmb = tid >> 2, ii = tid & 3;
        int e = (cmb >> 4) * 4 + ii;
        #pragma unroll
        for (int j = 0; j < 4; ++j) {
            int o = (cmb & 15) * 4 + j;
            float add = vsum[j] * (1.f / 4356.f);
            if (yp == 0) add += 260.f * fmaxf(c3_b[o], 0.f) * (1.f / 4356.f);
            atomicAdd(&out[(b * E + e) * F + o], add);
        }
    }
}

// ---------------------------------------------------------------------------
extern "C" void kernel_launch(void* const* d_in, const int* in_sizes, int n_in,
                              void* d_out, int out_size, void* d_ws, size_t ws_size,
                              hipStream_t stream) {
    (void)in_sizes; (void)n_in; (void)out_size; (void)ws_size;
    const float* state  = (const float*)d_in[0];
    const float* pre_w  = (const float*)d_in[1];
    const float* pre_b  = (const float*)d_in[2];
    const float* attn_w = (const float*)d_in[3];
    const float* attn_b = (const float*)d_in[4];
    const float* c3_w   = (const float*)d_in[5];
    const float* c3_b   = (const float*)d_in[6];

    float* out      = (float*)d_out;
    float* attn_out = out + B * E * F;

    char* ws = (char*)d_ws;
    constexpr size_t XT_BYTES = (size_t)B * H * YSTRIDE * 2;   // 8,650,752
    __bf16* xTs  = (__bf16*)ws;
    __bf16* wA1  = (__bf16*)(ws + XT_BYTES);
    __bf16* wA2  = (__bf16*)(ws + XT_BYTES + 73728);
    __bf16* wT3b = (__bf16*)(ws + XT_BYTES + 73728 + 18432);

    prep_kernel<<<1184, 256, 0, stream>>>(state, pre_w, attn_w, c3_w,
                                          xTs, wA1, wA2, wT3b, out);
    mega_kernel<<<dim3(H / 2, B), 256, 0, stream>>>(xTs, wA1, wA2, wT3b,
                                                    pre_b, attn_b, c3_b,
                                                    attn_out, out);
}